// Round 10
// baseline (87.689 us; speedup 1.0000x reference)
//
#include <hip/hip_runtime.h>
#include <hip/hip_bf16.h>

#define NB   4
#define CIN  64
#define COUT 64
#define HH   160
#define WW   160
#define HW   (HH * WW)

typedef __attribute__((ext_vector_type(8))) short bf16x8;   // 8 bf16 = 4 VGPR
typedef __attribute__((ext_vector_type(4))) float f32x4;
typedef __attribute__((ext_vector_type(2))) float f32x2;
typedef __attribute__((ext_vector_type(4))) unsigned int u32x4;

static __device__ __forceinline__ short f2bf(float v) {
    return __builtin_bit_cast(short, __float2bfloat16(v));
}

// ---------------------------------------------------------------------------
// Pre-pass 1: weight [O][C][3][3] f32 -> wtf in exact A-fragment order:
// wtf[t][ks][mt][lane][j]; a wave's A-frag load = one contiguous 1 KB block.
//   o = 16*mt + (lane&15),  c = 32*ks + 8*(lane>>4) + j
// ---------------------------------------------------------------------------
__global__ void wtf_kernel(const float* __restrict__ w, short* __restrict__ wtf) {
    int i = blockIdx.x * 256 + threadIdx.x;   // 9*2*4*64*8 = 36864
    if (i < 36864) {
        const int j  = i & 7;
        const int l  = (i >> 3) & 63;
        const int mt = (i >> 9) & 3;
        const int ks = (i >> 11) & 1;
        const int t  = i >> 12;
        const int o  = 16 * mt + (l & 15);
        const int c  = 32 * ks + 8 * (l >> 4) + j;
        wtf[i] = f2bf(w[(o * CIN + c) * 9 + t]);
    }
}

// ---------------------------------------------------------------------------
// Pre-pass 2: input [B][C][H][W] f32 -> tin [B][H][W][C] bf16.
// ---------------------------------------------------------------------------
__global__ __launch_bounds__(256) void tin_kernel(const float* __restrict__ in,
                                                  short* __restrict__ tin) {
    const int gid = blockIdx.x * 256 + threadIdx.x;   // b*HW + hw
    if (gid >= NB * HW) return;
    const int b  = gid / HW;
    const int hw = gid - b * HW;
    const float* src = in + (size_t)b * CIN * HW + hw;
    short* dst = tin + (size_t)gid * CIN;
#pragma unroll
    for (int chunk = 0; chunk < 4; ++chunk) {
        union { u32x4 v; short s[8]; } p0, p1;
#pragma unroll
        for (int cc = 0; cc < 8; ++cc)
            p0.s[cc] = f2bf(src[(size_t)(chunk * 16 + cc) * HW]);
#pragma unroll
        for (int cc = 0; cc < 8; ++cc)
            p1.s[cc] = f2bf(src[(size_t)(chunk * 16 + 8 + cc) * HW]);
        *(u32x4*)(dst + chunk * 16)     = p0.v;
        *(u32x4*)(dst + chunk * 16 + 8) = p1.v;
    }
}

// Geometry for tap T -> 4 bilinear coefs + 4 corner pointers (from tb).
#define GEOM(T, C00, C01, C10, C11, Q00, Q01, Q10, Q11) do {                 \
    const int gky = (T) / 3, gkx = (T) - 3 * gky;                            \
    const float gsy = fy + (float)(gky - 1) * rate;                          \
    const float gsx = fx + (float)(gkx - 1) * rate;                          \
    const float gy0f = floorf(gsy), gx0f = floorf(gsx);                      \
    const float gwy = gsy - gy0f, gwx = gsx - gx0f;                          \
    const int gy0 = (int)gy0f, gx0 = (int)gx0f;                              \
    const int gy1 = gy0 + 1, gx1 = gx0 + 1;                                  \
    const float gomwy = 1.0f - gwy, gomwx = 1.0f - gwx;                      \
    const float gvy0 = (gy0 >= 0 && gy0 < HH) ? 1.0f : 0.0f;                 \
    const float gvy1 = (gy1 >= 0 && gy1 < HH) ? 1.0f : 0.0f;                 \
    const float gvx0 = (gx0 >= 0 && gx0 < WW) ? 1.0f : 0.0f;                 \
    const float gvx1 = (gx1 >= 0 && gx1 < WW) ? 1.0f : 0.0f;                 \
    C00 = gomwy * gomwx * gvy0 * gvx0;                                       \
    C01 = gomwy * gwx   * gvy0 * gvx1;                                       \
    C10 = gwy   * gomwx * gvy1 * gvx0;                                       \
    C11 = gwy   * gwx   * gvy1 * gvx1;                                       \
    const int gcy0 = min(max(gy0, 0), HH - 1);                               \
    const int gcy1 = min(max(gy1, 0), HH - 1);                               \
    const int gcx0 = min(max(gx0, 0), WW - 1);                               \
    const int gcx1 = min(max(gx1, 0), WW - 1);                               \
    Q00 = tb + (size_t)(gcy0 * WW + gcx0) * CIN;                             \
    Q01 = tb + (size_t)(gcy0 * WW + gcx1) * CIN;                             \
    Q10 = tb + (size_t)(gcy1 * WW + gcx0) * CIN;                             \
    Q11 = tb + (size_t)(gcy1 * WW + gcx1) * CIN;                             \
} while (0)

// Blend 8 channels (4 dwords of packed bf16 pairs) + 4 MFMA rank-updates.
// Packed f32 math (v_pk_fma_f32) + 1 v_cvt_pk_bf16_f32 per dword.
static __device__ __forceinline__ void consume_tap(
    const u32x4 v00, const u32x4 v01, const u32x4 v10, const u32x4 v11,
    const float c00, const float c01, const float c10, const float c11,
    const bf16x8 wf0, const bf16x8 wf1, const bf16x8 wf2, const bf16x8 wf3,
    f32x4 acc[4])
{
    union { bf16x8 v; unsigned u[4]; } pf;
#pragma unroll
    for (int wd = 0; wd < 4; ++wd) {
        f32x2 s;
        {
            const unsigned u0 = v00[wd];
            const f32x2 xv = { __builtin_bit_cast(float, u0 << 16),
                               __builtin_bit_cast(float, u0 & 0xffff0000u) };
            s = c00 * xv;
        }
        {
            const unsigned u0 = v01[wd];
            const f32x2 xv = { __builtin_bit_cast(float, u0 << 16),
                               __builtin_bit_cast(float, u0 & 0xffff0000u) };
            s += c01 * xv;
        }
        {
            const unsigned u0 = v10[wd];
            const f32x2 xv = { __builtin_bit_cast(float, u0 << 16),
                               __builtin_bit_cast(float, u0 & 0xffff0000u) };
            s += c10 * xv;
        }
        {
            const unsigned u0 = v11[wd];
            const f32x2 xv = { __builtin_bit_cast(float, u0 << 16),
                               __builtin_bit_cast(float, u0 & 0xffff0000u) };
            s += c11 * xv;
        }
        unsigned r;
        asm("v_cvt_pk_bf16_f32 %0, %1, %2" : "=v"(r) : "v"(s.x), "v"(s.y));
        pf.u[wd] = r;
    }
    acc[0] = __builtin_amdgcn_mfma_f32_16x16x32_bf16(wf0, pf.v, acc[0], 0, 0, 0);
    acc[1] = __builtin_amdgcn_mfma_f32_16x16x32_bf16(wf1, pf.v, acc[1], 0, 0, 0);
    acc[2] = __builtin_amdgcn_mfma_f32_16x16x32_bf16(wf2, pf.v, acc[2], 0, 0, 0);
    acc[3] = __builtin_amdgcn_mfma_f32_16x16x32_bf16(wf3, pf.v, acc[3], 0, 0, 0);
}

// ---------------------------------------------------------------------------
// Main kernel: block = 4 waves = 2 strips x 2 K-halves (split-K). Per tap:
// 4 NHWC input loads (16 B) + 4 weight frags + 4 MFMA. Fully-unrolled tap
// loop with a 3-slot input window (depth-2 prefetch: tap t+2's loads issue
// before tap t's consume) and 2-slot weight window (depth-1). All window
// indices compile-time (rule #20). Pair-reduction via LDS (stride 17).
// ---------------------------------------------------------------------------
__global__ __launch_bounds__(256, 3) void pdconv_split_kernel(
    const short* __restrict__ tin,       // [B][H][W][CIN] bf16
    const short* __restrict__ wtf,       // frag-ordered weights bf16
    const float* __restrict__ rate_map,  // [B][1][H][W] f32
    const float* __restrict__ bias,      // [COUT] f32
    float* __restrict__ out)             // [B][COUT][H][W] f32
{
    const int tid   = threadIdx.x;
    const int wave  = tid >> 6;
    const int lane  = tid & 63;
    const int px    = lane & 15;
    const int g     = lane >> 4;
    const int strip = wave >> 1;
    const int ks    = wave & 1;

    // XCD-bijective swizzle (3200 % 8 == 0)
    const int cpx = gridDim.x >> 3;                     // 400
    const int bid = (blockIdx.x & 7) * cpx + (blockIdx.x >> 3);

    const int base = bid * 32 + strip * 16;             // this wave's strip
    const int b    = base / HW;
    const int pix0 = base - b * HW;
    const int y    = pix0 / WW;                         // 16 | 160
    const int x0   = pix0 - y * WW;
    const int x    = x0 + px;

    const float rate = rate_map[base + px];
    const float fy = (float)y, fx = (float)x;

    const short* tb  = tin + (size_t)b * HW * CIN + 32 * ks + 8 * g;
    const short* wtb = wtf + (size_t)ks * 2048 + lane * 8;   // + t*4096 + mt*512

    f32x4 acc[4];
#pragma unroll
    for (int mt = 0; mt < 4; ++mt) acc[mt] = (f32x4){0.f, 0.f, 0.f, 0.f};

    // ---- rolling windows (indices constant after full unroll) ----
    u32x4 w00[3], w01[3], w10[3], w11[3];
    float cf[3][4];
    bf16x8 wfr[2][4];

#define LOADIN(T, S) do {                                                    \
    const short *r00, *r01, *r10, *r11;                                      \
    GEOM(T, cf[S][0], cf[S][1], cf[S][2], cf[S][3], r00, r01, r10, r11);     \
    w00[S] = *(const u32x4*)r00; w01[S] = *(const u32x4*)r01;                \
    w10[S] = *(const u32x4*)r10; w11[S] = *(const u32x4*)r11;                \
} while (0)

#define LOADW(T, S) do {                                                     \
    const short* wb = wtb + (size_t)(T) * 4096;                              \
    wfr[S][0] = *(const bf16x8*)(wb);                                        \
    wfr[S][1] = *(const bf16x8*)(wb + 512);                                  \
    wfr[S][2] = *(const bf16x8*)(wb + 1024);                                 \
    wfr[S][3] = *(const bf16x8*)(wb + 1536);                                 \
} while (0)

    // prologue: inputs for taps 0,1; weights for tap 0
    LOADIN(0, 0);
    LOADIN(1, 1);
    LOADW(0, 0);

#pragma unroll
    for (int t = 0; t < 9; ++t) {
        const int s  = t % 3;           // constant after unroll
        const int sp = (t + 2) % 3;
        if (t < 7) LOADIN(t + 2, sp);   // depth-2 input prefetch
        if (t < 8) LOADW(t + 1, (t + 1) & 1);
        consume_tap(w00[s], w01[s], w10[s], w11[s],
                    cf[s][0], cf[s][1], cf[s][2], cf[s][3],
                    wfr[t & 1][0], wfr[t & 1][1], wfr[t & 1][2], wfr[t & 1][3],
                    acc);
    }
#undef LOADIN
#undef LOADW

    // ---- pair reduction: ks=1 -> LDS, ks=0 adds + stores ----
    __shared__ float red[2][64][17];     // stride 17: gcd(17,32)=1 -> free
    if (ks == 1) {
#pragma unroll
        for (int mt = 0; mt < 4; ++mt)
#pragma unroll
            for (int r = 0; r < 4; ++r)
                red[strip][lane][4 * mt + r] = acc[mt][r];
    }
    __syncthreads();
    if (ks == 0) {
        float* op = out + (size_t)b * COUT * HW + pix0 + px;
#pragma unroll
        for (int mt = 0; mt < 4; ++mt) {
            const f32x4 bv = *(const f32x4*)(bias + 16 * mt + 4 * g);
#pragma unroll
            for (int r = 0; r < 4; ++r) {
                const int o = 16 * mt + 4 * g + r;
                op[(size_t)o * HW] = acc[mt][r] + red[strip][lane][4 * mt + r] + bv[r];
            }
        }
    }
}

// ---------------------------------------------------------------------------
// Fallback (round-7 NCHW path) if ws_size can't hold the transposed input.
// ---------------------------------------------------------------------------
__global__ void wt2_kernel(const float* __restrict__ w, short* __restrict__ wt2) {
    int i = blockIdx.x * 256 + threadIdx.x;
    if (i < 9 * COUT * CIN) {
        int c = i & 63, o = (i >> 6) & 63, t = i >> 12;
        wt2[i] = f2bf(w[(o * CIN + c) * 9 + t]);
    }
}

__global__ __launch_bounds__(256) void pdconv_mfma_kernel(
    const float* __restrict__ in, const short* __restrict__ wt2,
    const float* __restrict__ rate_map, const float* __restrict__ bias,
    float* __restrict__ out)
{
    const int tid = threadIdx.x, wave = tid >> 6, lane = tid & 63;
    const int px = lane & 15, g = lane >> 4;
    const int cpx = gridDim.x >> 3;
    const int bid = (blockIdx.x & 7) * cpx + (blockIdx.x >> 3);
    const int base = bid * 64 + wave * 16;
    const int b = base / HW, pix0 = base - b * HW;
    const int y = pix0 / WW, x0 = pix0 - y * WW, x = x0 + px;
    const float rate = rate_map[base + px];
    const float fy = (float)y, fx = (float)x;
    f32x4 acc[4];
#pragma unroll
    for (int mt = 0; mt < 4; ++mt) acc[mt] = (f32x4){0.f, 0.f, 0.f, 0.f};
    const float* img  = in + (size_t)b * CIN * HW;
    const float* imgg = img + (size_t)g * 8 * HW;
#pragma unroll 1
    for (int t = 0; t < 9; ++t) {
        const int ky = t / 3, kx = t - 3 * ky;
        const float sy = fy + (float)(ky - 1) * rate;
        const float sx = fx + (float)(kx - 1) * rate;
        const float y0f = floorf(sy), x0f = floorf(sx);
        const float wy = sy - y0f, wx = sx - x0f;
        const int y0 = (int)y0f, x0i = (int)x0f, y1 = y0 + 1, x1 = x0i + 1;
        const float omwy = 1.0f - wy, omwx = 1.0f - wx;
        const float vy0 = (y0 >= 0 && y0 < HH) ? 1.0f : 0.0f;
        const float vy1 = (y1 >= 0 && y1 < HH) ? 1.0f : 0.0f;
        const float vx0 = (x0i >= 0 && x0i < WW) ? 1.0f : 0.0f;
        const float vx1 = (x1 >= 0 && x1 < WW) ? 1.0f : 0.0f;
        const float c00 = omwy * omwx * vy0 * vx0, c01 = omwy * wx * vy0 * vx1;
        const float c10 = wy * omwx * vy1 * vx0,  c11 = wy * wx * vy1 * vx1;
        const int cy0 = min(max(y0, 0), HH - 1), cy1 = min(max(y1, 0), HH - 1);
        const int cx0 = min(max(x0i, 0), WW - 1), cx1 = min(max(x1, 0), WW - 1);
        const int i00 = cy0 * WW + cx0, i01 = cy0 * WW + cx1;
        const int i10 = cy1 * WW + cx0, i11 = cy1 * WW + cx1;
#pragma unroll
        for (int ks = 0; ks < 2; ++ks) {
            bf16x8 wf[4];
#pragma unroll
            for (int mt = 0; mt < 4; ++mt)
                wf[mt] = *(const bf16x8*)(wt2 +
                          ((t * COUT + 16 * mt + px) * CIN + 32 * ks + 8 * g));
            float a[8];
#pragma unroll
            for (int j = 0; j < 8; ++j) {
                const float* ch = imgg + (size_t)(32 * ks + j) * HW;
                a[j] = c00 * ch[i00] + c01 * ch[i01] + c10 * ch[i10] + c11 * ch[i11];
            }
            union { bf16x8 v; short s[8]; } pf;
#pragma unroll
            for (int j = 0; j < 8; ++j) pf.s[j] = f2bf(a[j]);
#pragma unroll
            for (int mt = 0; mt < 4; ++mt)
                acc[mt] = __builtin_amdgcn_mfma_f32_16x16x32_bf16(
                              wf[mt], pf.v, acc[mt], 0, 0, 0);
        }
    }
    float* op = out + (size_t)b * COUT * HW + pix0 + px;
#pragma unroll
    for (int mt = 0; mt < 4; ++mt)
#pragma unroll
        for (int r = 0; r < 4; ++r) {
            const int o = 16 * mt + 4 * g + r;
            op[(size_t)o * HW] = acc[mt][r] + bias[o];
        }
}

extern "C" void kernel_launch(void* const* d_in, const int* in_sizes, int n_in,
                              void* d_out, int out_size, void* d_ws, size_t ws_size,
                              hipStream_t stream) {
    (void)in_sizes; (void)n_in; (void)out_size;
    const float* in   = (const float*)d_in[0];
    const float* w    = (const float*)d_in[1];
    const float* rm   = (const float*)d_in[2];
    const float* bias = (const float*)d_in[3];
    float* out = (float*)d_out;

    const size_t WTF_BYTES = 36864 * sizeof(short);                 // 73,728
    const size_t TIN_BYTES = (size_t)NB * HW * CIN * sizeof(short); // 13,107,200

    if (ws_size >= WTF_BYTES + TIN_BYTES) {
        short* wtf = (short*)d_ws;
        short* tin = (short*)((char*)d_ws + WTF_BYTES);
        hipLaunchKernelGGL(wtf_kernel, dim3(144), dim3(256), 0, stream, w, wtf);
        hipLaunchKernelGGL(tin_kernel, dim3((NB * HW + 255) / 256), dim3(256),
                           0, stream, in, tin);
        const int nblocks = (NB * HW) / 32;   // 3200: 2 strips / block
        hipLaunchKernelGGL(pdconv_split_kernel, dim3(nblocks), dim3(256), 0,
                           stream, tin, wtf, rm, bias, out);
    } else {
        short* wt2 = (short*)d_ws;   // 73,728 B
        hipLaunchKernelGGL(wt2_kernel, dim3(144), dim3(256), 0, stream, w, wt2);
        const int nblocks = (NB * HW) / 64;   // 1600
        hipLaunchKernelGGL(pdconv_mfma_kernel, dim3(nblocks), dim3(256), 0,
                           stream, in, wt2, rm, bias, out);
    }
}

// Round 11
// 86.545 us; speedup vs baseline: 1.0132x; 1.0132x over previous
//
#include <hip/hip_runtime.h>
#include <hip/hip_bf16.h>

#define NB   4
#define CIN  64
#define COUT 64
#define HH   160
#define WW   160
#define HW   (HH * WW)

typedef __attribute__((ext_vector_type(8))) short bf16x8;   // 8 bf16 = 4 VGPR
typedef __attribute__((ext_vector_type(4))) float f32x4;
typedef __attribute__((ext_vector_type(2))) float f32x2;
typedef __attribute__((ext_vector_type(4))) unsigned int u32x4;

static __device__ __forceinline__ short f2bf(float v) {
    return __builtin_bit_cast(short, __float2bfloat16(v));
}

// ---------------------------------------------------------------------------
// Pre-pass 1: weight [O][C][3][3] f32 -> wtf in exact A-fragment order:
// wtf[t][ks][mt][lane][j]; a wave's A-frag load = one contiguous 1 KB block.
//   o = 16*mt + (lane&15),  c = 32*ks + 8*(lane>>4) + j
// ---------------------------------------------------------------------------
__global__ void wtf_kernel(const float* __restrict__ w, short* __restrict__ wtf) {
    int i = blockIdx.x * 256 + threadIdx.x;   // 9*2*4*64*8 = 36864
    if (i < 36864) {
        const int j  = i & 7;
        const int l  = (i >> 3) & 63;
        const int mt = (i >> 9) & 3;
        const int ks = (i >> 11) & 1;
        const int t  = i >> 12;
        const int o  = 16 * mt + (l & 15);
        const int c  = 32 * ks + 8 * (l >> 4) + j;
        wtf[i] = f2bf(w[(o * CIN + c) * 9 + t]);
    }
}

// ---------------------------------------------------------------------------
// Pre-pass 2: input [B][C][H][W] f32 -> tin [B][H][W][C] bf16.
// ---------------------------------------------------------------------------
__global__ __launch_bounds__(256) void tin_kernel(const float* __restrict__ in,
                                                  short* __restrict__ tin) {
    const int gid = blockIdx.x * 256 + threadIdx.x;   // b*HW + hw
    if (gid >= NB * HW) return;
    const int b  = gid / HW;
    const int hw = gid - b * HW;
    const float* src = in + (size_t)b * CIN * HW + hw;
    short* dst = tin + (size_t)gid * CIN;
#pragma unroll
    for (int chunk = 0; chunk < 4; ++chunk) {
        union { u32x4 v; short s[8]; } p0, p1;
#pragma unroll
        for (int cc = 0; cc < 8; ++cc)
            p0.s[cc] = f2bf(src[(size_t)(chunk * 16 + cc) * HW]);
#pragma unroll
        for (int cc = 0; cc < 8; ++cc)
            p1.s[cc] = f2bf(src[(size_t)(chunk * 16 + 8 + cc) * HW]);
        *(u32x4*)(dst + chunk * 16)     = p0.v;
        *(u32x4*)(dst + chunk * 16 + 8) = p1.v;
    }
}

// Geometry for tap T at (fy, FX) with RATE -> 4 coefs + 4 corner pointers.
#define GEOM(T, RATE, FX, C00, C01, C10, C11, Q00, Q01, Q10, Q11) do {       \
    const int gky = (T) / 3, gkx = (T) - 3 * gky;                            \
    const float gsy = fy + (float)(gky - 1) * (RATE);                        \
    const float gsx = (FX) + (float)(gkx - 1) * (RATE);                      \
    const float gy0f = floorf(gsy), gx0f = floorf(gsx);                      \
    const float gwy = gsy - gy0f, gwx = gsx - gx0f;                          \
    const int gy0 = (int)gy0f, gx0 = (int)gx0f;                              \
    const int gy1 = gy0 + 1, gx1 = gx0 + 1;                                  \
    const float gomwy = 1.0f - gwy, gomwx = 1.0f - gwx;                      \
    const float gvy0 = (gy0 >= 0 && gy0 < HH) ? 1.0f : 0.0f;                 \
    const float gvy1 = (gy1 >= 0 && gy1 < HH) ? 1.0f : 0.0f;                 \
    const float gvx0 = (gx0 >= 0 && gx0 < WW) ? 1.0f : 0.0f;                 \
    const float gvx1 = (gx1 >= 0 && gx1 < WW) ? 1.0f : 0.0f;                 \
    C00 = gomwy * gomwx * gvy0 * gvx0;                                       \
    C01 = gomwy * gwx   * gvy0 * gvx1;                                       \
    C10 = gwy   * gomwx * gvy1 * gvx0;                                       \
    C11 = gwy   * gwx   * gvy1 * gvx1;                                       \
    const int gcy0 = min(max(gy0, 0), HH - 1);                               \
    const int gcy1 = min(max(gy1, 0), HH - 1);                               \
    const int gcx0 = min(max(gx0, 0), WW - 1);                               \
    const int gcx1 = min(max(gx1, 0), WW - 1);                               \
    Q00 = tb + (size_t)(gcy0 * WW + gcx0) * CIN;                             \
    Q01 = tb + (size_t)(gcy0 * WW + gcx1) * CIN;                             \
    Q10 = tb + (size_t)(gcy1 * WW + gcx0) * CIN;                             \
    Q11 = tb + (size_t)(gcy1 * WW + gcx1) * CIN;                             \
} while (0)

// Blend 8 channels (4 dwords of packed bf16 pairs) + 4 MFMA rank-updates.
static __device__ __forceinline__ void consume_tap(
    const u32x4 v00, const u32x4 v01, const u32x4 v10, const u32x4 v11,
    const float c00, const float c01, const float c10, const float c11,
    const bf16x8 wf0, const bf16x8 wf1, const bf16x8 wf2, const bf16x8 wf3,
    f32x4 acc[4])
{
    union { bf16x8 v; unsigned u[4]; } pf;
#pragma unroll
    for (int wd = 0; wd < 4; ++wd) {
        f32x2 s;
        {
            const unsigned u0 = v00[wd];
            const f32x2 xv = { __builtin_bit_cast(float, u0 << 16),
                               __builtin_bit_cast(float, u0 & 0xffff0000u) };
            s = c00 * xv;
        }
        {
            const unsigned u0 = v01[wd];
            const f32x2 xv = { __builtin_bit_cast(float, u0 << 16),
                               __builtin_bit_cast(float, u0 & 0xffff0000u) };
            s += c01 * xv;
        }
        {
            const unsigned u0 = v10[wd];
            const f32x2 xv = { __builtin_bit_cast(float, u0 << 16),
                               __builtin_bit_cast(float, u0 & 0xffff0000u) };
            s += c10 * xv;
        }
        {
            const unsigned u0 = v11[wd];
            const f32x2 xv = { __builtin_bit_cast(float, u0 << 16),
                               __builtin_bit_cast(float, u0 & 0xffff0000u) };
            s += c11 * xv;
        }
        unsigned r;
        asm("v_cvt_pk_bf16_f32 %0, %1, %2" : "=v"(r) : "v"(s.x), "v"(s.y));
        pf.u[wd] = r;
    }
    acc[0] = __builtin_amdgcn_mfma_f32_16x16x32_bf16(wf0, pf.v, acc[0], 0, 0, 0);
    acc[1] = __builtin_amdgcn_mfma_f32_16x16x32_bf16(wf1, pf.v, acc[1], 0, 0, 0);
    acc[2] = __builtin_amdgcn_mfma_f32_16x16x32_bf16(wf2, pf.v, acc[2], 0, 0, 0);
    acc[3] = __builtin_amdgcn_mfma_f32_16x16x32_bf16(wf3, pf.v, acc[3], 0, 0, 0);
}

// ---------------------------------------------------------------------------
// Main kernel: block = 4 waves = 2 strip-PAIRS x 2 K-halves. Each wave owns
// 32 px (two adjacent 16-px strips) x 32 ch: per tap 8 input loads +
// 4 weight frags (weights amortize over 2x px -> VMEM/px drops 1.8x) +
// 8 MFMA. Two strips = two independent dependency chains (2x MLP).
// Fully-unrolled tap loop, 3-slot input window (depth-2), 2-slot weights;
// launch_bounds(256,2) leaves VGPR room so windows actually stay live
// (round-10 lesson: at bounds(256,3) the scheduler re-serialized them).
// Pair-reduction via LDS (stride 17 -> conflict-free), static indexing.
// ---------------------------------------------------------------------------
__global__ __launch_bounds__(256, 2) void pdconv_pair_kernel(
    const short* __restrict__ tin,       // [B][H][W][CIN] bf16
    const short* __restrict__ wtf,       // frag-ordered weights bf16
    const float* __restrict__ rate_map,  // [B][1][H][W] f32
    const float* __restrict__ bias,      // [COUT] f32
    float* __restrict__ out)             // [B][COUT][H][W] f32
{
    const int tid  = threadIdx.x;
    const int wave = tid >> 6;
    const int lane = tid & 63;
    const int px   = lane & 15;
    const int g    = lane >> 4;
    const int pair = wave >> 1;
    const int ks   = wave & 1;

    // XCD-bijective swizzle (1600 % 8 == 0)
    const int cpx = gridDim.x >> 3;                     // 200
    const int bid = (blockIdx.x & 7) * cpx + (blockIdx.x >> 3);

    const int base = bid * 64 + pair * 32;              // strip-pair origin
    const int b    = base / HW;
    const int pix0 = base - b * HW;
    const int y    = pix0 / WW;                         // 32 | 160
    const int x0   = pix0 - y * WW;

    const float rate0 = rate_map[base + px];
    const float rate1 = rate_map[base + 16 + px];
    const float fy  = (float)y;
    const float fx0 = (float)(x0 + px);
    const float fx1 = (float)(x0 + 16 + px);

    const short* tb  = tin + (size_t)b * HW * CIN + 32 * ks + 8 * g;
    const short* wtb = wtf + (size_t)ks * 2048 + lane * 8;   // + t*4096 + mt*512

    f32x4 acc[2][4];
#pragma unroll
    for (int s = 0; s < 2; ++s)
#pragma unroll
        for (int mt = 0; mt < 4; ++mt) acc[s][mt] = (f32x4){0.f, 0.f, 0.f, 0.f};

    // ---- rolling windows (all indices constant after full unroll) ----
    u32x4 wi00[2][3], wi01[2][3], wi10[2][3], wi11[2][3];
    float cf[2][3][4];
    bf16x8 wfr[2][4];

#define LOADIN(S, RATE, FX, T, SL) do {                                      \
    const short *r00, *r01, *r10, *r11;                                      \
    GEOM(T, RATE, FX, cf[S][SL][0], cf[S][SL][1], cf[S][SL][2], cf[S][SL][3],\
         r00, r01, r10, r11);                                                \
    wi00[S][SL] = *(const u32x4*)r00; wi01[S][SL] = *(const u32x4*)r01;      \
    wi10[S][SL] = *(const u32x4*)r10; wi11[S][SL] = *(const u32x4*)r11;      \
} while (0)

#define LOADW(T, SL) do {                                                    \
    const short* wb = wtb + (size_t)(T) * 4096;                              \
    wfr[SL][0] = *(const bf16x8*)(wb);                                       \
    wfr[SL][1] = *(const bf16x8*)(wb + 512);                                 \
    wfr[SL][2] = *(const bf16x8*)(wb + 1024);                                \
    wfr[SL][3] = *(const bf16x8*)(wb + 1536);                                \
} while (0)

    // prologue: inputs for taps 0,1 (both strips); weights for tap 0
    LOADIN(0, rate0, fx0, 0, 0);
    LOADIN(1, rate1, fx1, 0, 0);
    LOADIN(0, rate0, fx0, 1, 1);
    LOADIN(1, rate1, fx1, 1, 1);
    LOADW(0, 0);

#pragma unroll
    for (int t = 0; t < 9; ++t) {
        const int s  = t % 3;           // constant after unroll
        const int sp = (t + 2) % 3;
        if (t < 7) {
            LOADIN(0, rate0, fx0, t + 2, sp);   // depth-2 input prefetch
            LOADIN(1, rate1, fx1, t + 2, sp);
        }
        if (t < 8) LOADW(t + 1, (t + 1) & 1);
        consume_tap(wi00[0][s], wi01[0][s], wi10[0][s], wi11[0][s],
                    cf[0][s][0], cf[0][s][1], cf[0][s][2], cf[0][s][3],
                    wfr[t & 1][0], wfr[t & 1][1], wfr[t & 1][2], wfr[t & 1][3],
                    acc[0]);
        consume_tap(wi00[1][s], wi01[1][s], wi10[1][s], wi11[1][s],
                    cf[1][s][0], cf[1][s][1], cf[1][s][2], cf[1][s][3],
                    wfr[t & 1][0], wfr[t & 1][1], wfr[t & 1][2], wfr[t & 1][3],
                    acc[1]);
    }
#undef LOADIN
#undef LOADW

    // ---- pair reduction: ks=1 -> LDS, ks=0 adds + stores ----
    __shared__ float red[2][2][64][17];   // [pair][strip]; stride 17 -> free
    if (ks == 1) {
#pragma unroll
        for (int s = 0; s < 2; ++s)
#pragma unroll
            for (int mt = 0; mt < 4; ++mt)
#pragma unroll
                for (int r = 0; r < 4; ++r)
                    red[pair][s][lane][4 * mt + r] = acc[s][mt][r];
    }
    __syncthreads();
    if (ks == 0) {
#pragma unroll
        for (int s = 0; s < 2; ++s) {
            float* op = out + (size_t)b * COUT * HW + pix0 + 16 * s + px;
#pragma unroll
            for (int mt = 0; mt < 4; ++mt) {
                const f32x4 bv = *(const f32x4*)(bias + 16 * mt + 4 * g);
#pragma unroll
                for (int r = 0; r < 4; ++r) {
                    const int o = 16 * mt + 4 * g + r;
                    op[(size_t)o * HW] = acc[s][mt][r]
                                       + red[pair][s][lane][4 * mt + r] + bv[r];
                }
            }
        }
    }
}

// ---------------------------------------------------------------------------
// Fallback (round-7 NCHW path) if ws_size can't hold the transposed input.
// ---------------------------------------------------------------------------
__global__ void wt2_kernel(const float* __restrict__ w, short* __restrict__ wt2) {
    int i = blockIdx.x * 256 + threadIdx.x;
    if (i < 9 * COUT * CIN) {
        int c = i & 63, o = (i >> 6) & 63, t = i >> 12;
        wt2[i] = f2bf(w[(o * CIN + c) * 9 + t]);
    }
}

__global__ __launch_bounds__(256) void pdconv_mfma_kernel(
    const float* __restrict__ in, const short* __restrict__ wt2,
    const float* __restrict__ rate_map, const float* __restrict__ bias,
    float* __restrict__ out)
{
    const int tid = threadIdx.x, wave = tid >> 6, lane = tid & 63;
    const int px = lane & 15, g = lane >> 4;
    const int cpx = gridDim.x >> 3;
    const int bid = (blockIdx.x & 7) * cpx + (blockIdx.x >> 3);
    const int base = bid * 64 + wave * 16;
    const int b = base / HW, pix0 = base - b * HW;
    const int y = pix0 / WW, x0 = pix0 - y * WW, x = x0 + px;
    const float rate = rate_map[base + px];
    const float fy = (float)y, fx = (float)x;
    f32x4 acc[4];
#pragma unroll
    for (int mt = 0; mt < 4; ++mt) acc[mt] = (f32x4){0.f, 0.f, 0.f, 0.f};
    const float* img  = in + (size_t)b * CIN * HW;
    const float* imgg = img + (size_t)g * 8 * HW;
#pragma unroll 1
    for (int t = 0; t < 9; ++t) {
        const int ky = t / 3, kx = t - 3 * ky;
        const float sy = fy + (float)(ky - 1) * rate;
        const float sx = fx + (float)(kx - 1) * rate;
        const float y0f = floorf(sy), x0f = floorf(sx);
        const float wy = sy - y0f, wx = sx - x0f;
        const int y0 = (int)y0f, x0i = (int)x0f, y1 = y0 + 1, x1 = x0i + 1;
        const float omwy = 1.0f - wy, omwx = 1.0f - wx;
        const float vy0 = (y0 >= 0 && y0 < HH) ? 1.0f : 0.0f;
        const float vy1 = (y1 >= 0 && y1 < HH) ? 1.0f : 0.0f;
        const float vx0 = (x0i >= 0 && x0i < WW) ? 1.0f : 0.0f;
        const float vx1 = (x1 >= 0 && x1 < WW) ? 1.0f : 0.0f;
        const float c00 = omwy * omwx * vy0 * vx0, c01 = omwy * wx * vy0 * vx1;
        const float c10 = wy * omwx * vy1 * vx0,  c11 = wy * wx * vy1 * vx1;
        const int cy0 = min(max(y0, 0), HH - 1), cy1 = min(max(y1, 0), HH - 1);
        const int cx0 = min(max(x0i, 0), WW - 1), cx1 = min(max(x1, 0), WW - 1);
        const int i00 = cy0 * WW + cx0, i01 = cy0 * WW + cx1;
        const int i10 = cy1 * WW + cx0, i11 = cy1 * WW + cx1;
#pragma unroll
        for (int ks = 0; ks < 2; ++ks) {
            bf16x8 wf[4];
#pragma unroll
            for (int mt = 0; mt < 4; ++mt)
                wf[mt] = *(const bf16x8*)(wt2 +
                          ((t * COUT + 16 * mt + px) * CIN + 32 * ks + 8 * g));
            float a[8];
#pragma unroll
            for (int j = 0; j < 8; ++j) {
                const float* ch = imgg + (size_t)(32 * ks + j) * HW;
                a[j] = c00 * ch[i00] + c01 * ch[i01] + c10 * ch[i10] + c11 * ch[i11];
            }
            union { bf16x8 v; short s[8]; } pf;
#pragma unroll
            for (int j = 0; j < 8; ++j) pf.s[j] = f2bf(a[j]);
#pragma unroll
            for (int mt = 0; mt < 4; ++mt)
                acc[mt] = __builtin_amdgcn_mfma_f32_16x16x32_bf16(
                              wf[mt], pf.v, acc[mt], 0, 0, 0);
        }
    }
    float* op = out + (size_t)b * COUT * HW + pix0 + px;
#pragma unroll
    for (int mt = 0; mt < 4; ++mt)
#pragma unroll
        for (int r = 0; r < 4; ++r) {
            const int o = 16 * mt + 4 * g + r;
            op[(size_t)o * HW] = acc[mt][r] + bias[o];
        }
}

extern "C" void kernel_launch(void* const* d_in, const int* in_sizes, int n_in,
                              void* d_out, int out_size, void* d_ws, size_t ws_size,
                              hipStream_t stream) {
    (void)in_sizes; (void)n_in; (void)out_size;
    const float* in   = (const float*)d_in[0];
    const float* w    = (const float*)d_in[1];
    const float* rm   = (const float*)d_in[2];
    const float* bias = (const float*)d_in[3];
    float* out = (float*)d_out;

    const size_t WTF_BYTES = 36864 * sizeof(short);                 // 73,728
    const size_t TIN_BYTES = (size_t)NB * HW * CIN * sizeof(short); // 13,107,200

    if (ws_size >= WTF_BYTES + TIN_BYTES) {
        short* wtf = (short*)d_ws;
        short* tin = (short*)((char*)d_ws + WTF_BYTES);
        hipLaunchKernelGGL(wtf_kernel, dim3(144), dim3(256), 0, stream, w, wtf);
        hipLaunchKernelGGL(tin_kernel, dim3((NB * HW + 255) / 256), dim3(256),
                           0, stream, in, tin);
        const int nblocks = (NB * HW) / 64;   // 1600: 2 strip-pairs / block
        hipLaunchKernelGGL(pdconv_pair_kernel, dim3(nblocks), dim3(256), 0,
                           stream, tin, wtf, rm, bias, out);
    } else {
        short* wt2 = (short*)d_ws;   // 73,728 B
        hipLaunchKernelGGL(wt2_kernel, dim3(144), dim3(256), 0, stream, w, wt2);
        const int nblocks = (NB * HW) / 64;   // 1600
        hipLaunchKernelGGL(pdconv_mfma_kernel, dim3(nblocks), dim3(256), 0,
                           stream, in, wt2, rm, bias, out);
    }
}

// Round 12
// 82.233 us; speedup vs baseline: 1.0664x; 1.0524x over previous
//
#include <hip/hip_runtime.h>
#include <hip/hip_bf16.h>

#define NB   4
#define CIN  64
#define COUT 64
#define HH   160
#define WW   160
#define HW   (HH * WW)

typedef __attribute__((ext_vector_type(8))) short bf16x8;   // 8 bf16 = 4 VGPR
typedef __attribute__((ext_vector_type(4))) float f32x4;
typedef __attribute__((ext_vector_type(2))) float f32x2;
typedef __attribute__((ext_vector_type(4))) unsigned int u32x4;

static __device__ __forceinline__ short f2bf(float v) {
    return __builtin_bit_cast(short, __float2bfloat16(v));
}

// ---------------------------------------------------------------------------
// Pre-pass 1: weight [O][C][3][3] f32 -> wtf in exact A-fragment order:
// wtf[t][ks][mt][lane][j]; frag (t,ks,mt) = contiguous 1 KB, lane reads 16 B.
//   o = 16*mt + (lane&15),  c = 32*ks + 8*(lane>>4) + j
// ---------------------------------------------------------------------------
__global__ void wtf_kernel(const float* __restrict__ w, short* __restrict__ wtf) {
    int i = blockIdx.x * 256 + threadIdx.x;   // 9*2*4*64*8 = 36864
    if (i < 36864) {
        const int j  = i & 7;
        const int l  = (i >> 3) & 63;
        const int mt = (i >> 9) & 3;
        const int ks = (i >> 11) & 1;
        const int t  = i >> 12;
        const int o  = 16 * mt + (l & 15);
        const int c  = 32 * ks + 8 * (l >> 4) + j;
        wtf[i] = f2bf(w[(o * CIN + c) * 9 + t]);
    }
}

// ---------------------------------------------------------------------------
// Pre-pass 2: input [B][C][H][W] f32 -> tin [B][H][W][C] bf16.
// XCD-aligned: same bijective swizzle as the main kernel (400 % 8 == 0,
// cpx = 50) so the XCD that WRITES a pixel band is the XCD that READS it
// (round-11 lesson: un-swizzled writer vs swizzled reader -> every gather
// crossed to L3 instead of local L2).
// ---------------------------------------------------------------------------
__global__ __launch_bounds__(256) void tin_kernel(const float* __restrict__ in,
                                                  short* __restrict__ tin) {
    const int cpx = gridDim.x >> 3;                           // 50
    const int wb  = (blockIdx.x & 7) * cpx + (blockIdx.x >> 3);
    const int gid = wb * 256 + threadIdx.x;                   // b*HW + hw
    if (gid >= NB * HW) return;
    const int b  = gid / HW;
    const int hw = gid - b * HW;
    const float* src = in + (size_t)b * CIN * HW + hw;
    short* dst = tin + (size_t)gid * CIN;
#pragma unroll
    for (int chunk = 0; chunk < 4; ++chunk) {
        union { u32x4 v; short s[8]; } p0, p1;
#pragma unroll
        for (int cc = 0; cc < 8; ++cc)
            p0.s[cc] = f2bf(src[(size_t)(chunk * 16 + cc) * HW]);
#pragma unroll
        for (int cc = 0; cc < 8; ++cc)
            p1.s[cc] = f2bf(src[(size_t)(chunk * 16 + 8 + cc) * HW]);
        *(u32x4*)(dst + chunk * 16)     = p0.v;
        *(u32x4*)(dst + chunk * 16 + 8) = p1.v;
    }
}

// Geometry for tap T -> 4 bilinear coefs + 4 corner pointers (from tb).
#define GEOM(T, C00, C01, C10, C11, Q00, Q01, Q10, Q11) do {                 \
    const int gky = (T) / 3, gkx = (T) - 3 * gky;                            \
    const float gsy = fy + (float)(gky - 1) * rate;                          \
    const float gsx = fx + (float)(gkx - 1) * rate;                          \
    const float gy0f = floorf(gsy), gx0f = floorf(gsx);                      \
    const float gwy = gsy - gy0f, gwx = gsx - gx0f;                          \
    const int gy0 = (int)gy0f, gx0 = (int)gx0f;                              \
    const int gy1 = gy0 + 1, gx1 = gx0 + 1;                                  \
    const float gomwy = 1.0f - gwy, gomwx = 1.0f - gwx;                      \
    const float gvy0 = (gy0 >= 0 && gy0 < HH) ? 1.0f : 0.0f;                 \
    const float gvy1 = (gy1 >= 0 && gy1 < HH) ? 1.0f : 0.0f;                 \
    const float gvx0 = (gx0 >= 0 && gx0 < WW) ? 1.0f : 0.0f;                 \
    const float gvx1 = (gx1 >= 0 && gx1 < WW) ? 1.0f : 0.0f;                 \
    C00 = gomwy * gomwx * gvy0 * gvx0;                                       \
    C01 = gomwy * gwx   * gvy0 * gvx1;                                       \
    C10 = gwy   * gomwx * gvy1 * gvx0;                                       \
    C11 = gwy   * gwx   * gvy1 * gvx1;                                       \
    const int gcy0 = min(max(gy0, 0), HH - 1);                               \
    const int gcy1 = min(max(gy1, 0), HH - 1);                               \
    const int gcx0 = min(max(gx0, 0), WW - 1);                               \
    const int gcx1 = min(max(gx1, 0), WW - 1);                               \
    Q00 = tb + (size_t)(gcy0 * WW + gcx0) * CIN;                             \
    Q01 = tb + (size_t)(gcy0 * WW + gcx1) * CIN;                             \
    Q10 = tb + (size_t)(gcy1 * WW + gcx0) * CIN;                             \
    Q11 = tb + (size_t)(gcy1 * WW + gcx1) * CIN;                             \
} while (0)

// Blend 8 channels (4 dwords of packed bf16 pairs) + 4 MFMA rank-updates.
static __device__ __forceinline__ void consume_tap(
    const u32x4 v00, const u32x4 v01, const u32x4 v10, const u32x4 v11,
    const float c00, const float c01, const float c10, const float c11,
    const bf16x8 wf0, const bf16x8 wf1, const bf16x8 wf2, const bf16x8 wf3,
    f32x4 acc[4])
{
    union { bf16x8 v; unsigned u[4]; } pf;
#pragma unroll
    for (int wd = 0; wd < 4; ++wd) {
        f32x2 s;
        {
            const unsigned u0 = v00[wd];
            const f32x2 xv = { __builtin_bit_cast(float, u0 << 16),
                               __builtin_bit_cast(float, u0 & 0xffff0000u) };
            s = c00 * xv;
        }
        {
            const unsigned u0 = v01[wd];
            const f32x2 xv = { __builtin_bit_cast(float, u0 << 16),
                               __builtin_bit_cast(float, u0 & 0xffff0000u) };
            s += c01 * xv;
        }
        {
            const unsigned u0 = v10[wd];
            const f32x2 xv = { __builtin_bit_cast(float, u0 << 16),
                               __builtin_bit_cast(float, u0 & 0xffff0000u) };
            s += c10 * xv;
        }
        {
            const unsigned u0 = v11[wd];
            const f32x2 xv = { __builtin_bit_cast(float, u0 << 16),
                               __builtin_bit_cast(float, u0 & 0xffff0000u) };
            s += c11 * xv;
        }
        unsigned r;
        asm("v_cvt_pk_bf16_f32 %0, %1, %2" : "=v"(r) : "v"(s.x), "v"(s.y));
        pf.u[wd] = r;
    }
    acc[0] = __builtin_amdgcn_mfma_f32_16x16x32_bf16(wf0, pf.v, acc[0], 0, 0, 0);
    acc[1] = __builtin_amdgcn_mfma_f32_16x16x32_bf16(wf1, pf.v, acc[1], 0, 0, 0);
    acc[2] = __builtin_amdgcn_mfma_f32_16x16x32_bf16(wf2, pf.v, acc[2], 0, 0, 0);
    acc[3] = __builtin_amdgcn_mfma_f32_16x16x32_bf16(wf3, pf.v, acc[3], 0, 0, 0);
}

// ---------------------------------------------------------------------------
// Main kernel: 4 waves/block, each wave = one 16-px strip over the FULL
// K=576 (64 ch x 9 taps), acc[4] = all 64 outputs. Weights for taps 0..7
// are staged ONCE per block into 64 KB LDS (wtf layout is already frag
// order -> linear copy) and read via ds_read_b128: removes the per-wave
// redundant weight stream from the TA/L1 path (round-11 diagnosis: weight
// lines were ~50% of all line-requests, re-pulled by every wave). Tap 8's
// weights come from global, prefetched at t==7. Inputs: 8 NHWC 16 B loads
// per tap, depth-1 2-slot rolling window, fully unrolled (static indices).
// ---------------------------------------------------------------------------
__global__ __launch_bounds__(256, 2) void pdconv_lds_kernel(
    const short* __restrict__ tin,       // [B][H][W][CIN] bf16
    const short* __restrict__ wtf,       // frag-ordered weights bf16
    const float* __restrict__ rate_map,  // [B][1][H][W] f32
    const float* __restrict__ bias,      // [COUT] f32
    float* __restrict__ out)             // [B][COUT][H][W] f32
{
    __shared__ short wlds[32768];        // taps 0..7 = exactly 65,536 B

    const int tid  = threadIdx.x;
    const int wave = tid >> 6;
    const int lane = tid & 63;
    const int px   = lane & 15;
    const int g    = lane >> 4;

    // ---- stage weights (taps 0..7) -> LDS, fully coalesced ----
#pragma unroll
    for (int it = 0; it < 16; ++it) {
        const int so = (it * 256 + tid) * 8;   // short index, 16 B per thread
        *(u32x4*)(wlds + so) = *(const u32x4*)(wtf + so);
    }

    // XCD-bijective swizzle (1600 % 8 == 0)
    const int cpx = gridDim.x >> 3;                     // 200
    const int bid = (blockIdx.x & 7) * cpx + (blockIdx.x >> 3);

    const int base = bid * 64 + wave * 16;
    const int b    = base / HW;
    const int pix0 = base - b * HW;
    const int y    = pix0 / WW;                         // 16 | 160
    const int x0   = pix0 - y * WW;

    const float rate = rate_map[base + px];
    const float fy = (float)y, fx = (float)(x0 + px);

    const short* tb  = tin + (size_t)b * HW * CIN + 8 * g;  // + 32*ks at load
    const short* wgl = wtf + lane * 8;                      // tap-8 global base

    f32x4 acc[4];
#pragma unroll
    for (int mt = 0; mt < 4; ++mt) acc[mt] = (f32x4){0.f, 0.f, 0.f, 0.f};

    // ---- rolling input window: 2 slots x 2 ks, all indices compile-time ----
    u32x4 vi00[2][2], vi01[2][2], vi10[2][2], vi11[2][2];
    float cf[2][4];

#define LOADIN(T, SL) do {                                                   \
    const short *q00, *q01, *q10, *q11;                                      \
    GEOM(T, cf[SL][0], cf[SL][1], cf[SL][2], cf[SL][3], q00, q01, q10, q11); \
    vi00[SL][0] = *(const u32x4*)(q00);                                      \
    vi00[SL][1] = *(const u32x4*)(q00 + 32);                                 \
    vi01[SL][0] = *(const u32x4*)(q01);                                      \
    vi01[SL][1] = *(const u32x4*)(q01 + 32);                                 \
    vi10[SL][0] = *(const u32x4*)(q10);                                      \
    vi10[SL][1] = *(const u32x4*)(q10 + 32);                                 \
    vi11[SL][0] = *(const u32x4*)(q11);                                      \
    vi11[SL][1] = *(const u32x4*)(q11 + 32);                                 \
} while (0)

    // prologue: inputs for tap 0; then barrier for the staged weights
    LOADIN(0, 0);
    bf16x8 wf8[2][4];
    __syncthreads();

#pragma unroll
    for (int t = 0; t < 9; ++t) {
        const int s = t & 1;                   // constant after unroll
        if (t < 8) LOADIN(t + 1, (t + 1) & 1); // depth-1 input prefetch
        if (t == 7) {                          // prefetch tap-8 weights (global)
#pragma unroll
            for (int ks = 0; ks < 2; ++ks)
#pragma unroll
                for (int mt = 0; mt < 4; ++mt)
                    wf8[ks][mt] = *(const bf16x8*)(wgl +
                                   (size_t)((16 + ks) * 4 + mt) * 512);
        }
#pragma unroll
        for (int ks = 0; ks < 2; ++ks) {
            bf16x8 wfa, wfb, wfc, wfd;
            if (t < 8) {
                const short* wl = wlds + ((t * 2 + ks) * 4) * 512 + lane * 8;
                wfa = *(const bf16x8*)(wl);
                wfb = *(const bf16x8*)(wl + 512);
                wfc = *(const bf16x8*)(wl + 1024);
                wfd = *(const bf16x8*)(wl + 1536);
            } else {
                wfa = wf8[ks][0]; wfb = wf8[ks][1];
                wfc = wf8[ks][2]; wfd = wf8[ks][3];
            }
            consume_tap(vi00[s][ks], vi01[s][ks], vi10[s][ks], vi11[s][ks],
                        cf[s][0], cf[s][1], cf[s][2], cf[s][3],
                        wfa, wfb, wfc, wfd, acc);
        }
    }
#undef LOADIN

    // ---- epilogue: C col = px, row = 4g + r (+16mt) ----
    float* op = out + (size_t)b * COUT * HW + pix0 + px;
#pragma unroll
    for (int mt = 0; mt < 4; ++mt) {
        const f32x4 bv = *(const f32x4*)(bias + 16 * mt + 4 * g);
#pragma unroll
        for (int r = 0; r < 4; ++r) {
            const int o = 16 * mt + 4 * g + r;
            op[(size_t)o * HW] = acc[mt][r] + bv[r];
        }
    }
}

// ---------------------------------------------------------------------------
// Fallback (round-7 NCHW path) if ws_size can't hold the transposed input.
// ---------------------------------------------------------------------------
__global__ void wt2_kernel(const float* __restrict__ w, short* __restrict__ wt2) {
    int i = blockIdx.x * 256 + threadIdx.x;
    if (i < 9 * COUT * CIN) {
        int c = i & 63, o = (i >> 6) & 63, t = i >> 12;
        wt2[i] = f2bf(w[(o * CIN + c) * 9 + t]);
    }
}

__global__ __launch_bounds__(256) void pdconv_mfma_kernel(
    const float* __restrict__ in, const short* __restrict__ wt2,
    const float* __restrict__ rate_map, const float* __restrict__ bias,
    float* __restrict__ out)
{
    const int tid = threadIdx.x, wave = tid >> 6, lane = tid & 63;
    const int px = lane & 15, g = lane >> 4;
    const int cpx = gridDim.x >> 3;
    const int bid = (blockIdx.x & 7) * cpx + (blockIdx.x >> 3);
    const int base = bid * 64 + wave * 16;
    const int b = base / HW, pix0 = base - b * HW;
    const int y = pix0 / WW, x0 = pix0 - y * WW, x = x0 + px;
    const float rate = rate_map[base + px];
    const float fy = (float)y, fx = (float)x;
    f32x4 acc[4];
#pragma unroll
    for (int mt = 0; mt < 4; ++mt) acc[mt] = (f32x4){0.f, 0.f, 0.f, 0.f};
    const float* img  = in + (size_t)b * CIN * HW;
    const float* imgg = img + (size_t)g * 8 * HW;
#pragma unroll 1
    for (int t = 0; t < 9; ++t) {
        const int ky = t / 3, kx = t - 3 * ky;
        const float sy = fy + (float)(ky - 1) * rate;
        const float sx = fx + (float)(kx - 1) * rate;
        const float y0f = floorf(sy), x0f = floorf(sx);
        const float wy = sy - y0f, wx = sx - x0f;
        const int y0 = (int)y0f, x0i = (int)x0f, y1 = y0 + 1, x1 = x0i + 1;
        const float omwy = 1.0f - wy, omwx = 1.0f - wx;
        const float vy0 = (y0 >= 0 && y0 < HH) ? 1.0f : 0.0f;
        const float vy1 = (y1 >= 0 && y1 < HH) ? 1.0f : 0.0f;
        const float vx0 = (x0i >= 0 && x0i < WW) ? 1.0f : 0.0f;
        const float vx1 = (x1 >= 0 && x1 < WW) ? 1.0f : 0.0f;
        const float c00 = omwy * omwx * vy0 * vx0, c01 = omwy * wx * vy0 * vx1;
        const float c10 = wy * omwx * vy1 * vx0,  c11 = wy * wx * vy1 * vx1;
        const int cy0 = min(max(y0, 0), HH - 1), cy1 = min(max(y1, 0), HH - 1);
        const int cx0 = min(max(x0i, 0), WW - 1), cx1 = min(max(x1, 0), WW - 1);
        const int i00 = cy0 * WW + cx0, i01 = cy0 * WW + cx1;
        const int i10 = cy1 * WW + cx0, i11 = cy1 * WW + cx1;
#pragma unroll
        for (int ks = 0; ks < 2; ++ks) {
            bf16x8 wf[4];
#pragma unroll
            for (int mt = 0; mt < 4; ++mt)
                wf[mt] = *(const bf16x8*)(wt2 +
                          ((t * COUT + 16 * mt + px) * CIN + 32 * ks + 8 * g));
            float a[8];
#pragma unroll
            for (int j = 0; j < 8; ++j) {
                const float* ch = imgg + (size_t)(32 * ks + j) * HW;
                a[j] = c00 * ch[i00] + c01 * ch[i01] + c10 * ch[i10] + c11 * ch[i11];
            }
            union { bf16x8 v; short s[8]; } pf;
#pragma unroll
            for (int j = 0; j < 8; ++j) pf.s[j] = f2bf(a[j]);
#pragma unroll
            for (int mt = 0; mt < 4; ++mt)
                acc[mt] = __builtin_amdgcn_mfma_f32_16x16x32_bf16(
                              wf[mt], pf.v, acc[mt], 0, 0, 0);
        }
    }
    float* op = out + (size_t)b * COUT * HW + pix0 + px;
#pragma unroll
    for (int mt = 0; mt < 4; ++mt)
#pragma unroll
        for (int r = 0; r < 4; ++r) {
            const int o = 16 * mt + 4 * g + r;
            op[(size_t)o * HW] = acc[mt][r] + bias[o];
        }
}

extern "C" void kernel_launch(void* const* d_in, const int* in_sizes, int n_in,
                              void* d_out, int out_size, void* d_ws, size_t ws_size,
                              hipStream_t stream) {
    (void)in_sizes; (void)n_in; (void)out_size;
    const float* in   = (const float*)d_in[0];
    const float* w    = (const float*)d_in[1];
    const float* rm   = (const float*)d_in[2];
    const float* bias = (const float*)d_in[3];
    float* out = (float*)d_out;

    const size_t WTF_BYTES = 36864 * sizeof(short);                 // 73,728
    const size_t TIN_BYTES = (size_t)NB * HW * CIN * sizeof(short); // 13,107,200

    if (ws_size >= WTF_BYTES + TIN_BYTES) {
        short* wtf = (short*)d_ws;
        short* tin = (short*)((char*)d_ws + WTF_BYTES);
        hipLaunchKernelGGL(wtf_kernel, dim3(144), dim3(256), 0, stream, w, wtf);
        hipLaunchKernelGGL(tin_kernel, dim3((NB * HW) / 256), dim3(256),
                           0, stream, in, tin);
        const int nblocks = (NB * HW) / 64;   // 1600
        hipLaunchKernelGGL(pdconv_lds_kernel, dim3(nblocks), dim3(256), 0,
                           stream, tin, wtf, rm, bias, out);
    } else {
        short* wt2 = (short*)d_ws;   // 73,728 B
        hipLaunchKernelGGL(wt2_kernel, dim3(144), dim3(256), 0, stream, w, wt2);
        const int nblocks = (NB * HW) / 64;   // 1600
        hipLaunchKernelGGL(pdconv_mfma_kernel, dim3(nblocks), dim3(256), 0,
                           stream, in, wt2, rm, bias, out);
    }
}